// Round 14
// baseline (154.194 us; speedup 1.0000x reference)
//
#include <hip/hip_runtime.h>

#define N 8192
#define F 500
#define K2 512                        // F padded to MFMA-friendly K
#define NH 256
#define CAP (1 << 17)
#define BT 128                        // dist tile
#define NBT (N / BT)                  // 64
#define TRI2 (NBT * (NBT + 1) / 2)    // 2080 (%8==0)
#define MARGIN 16.0f                  // |d_fp8 - d_exact| safety bound for pass-2 filter

using bf16x8 = __attribute__((ext_vector_type(8))) short;
using f32x4  = __attribute__((ext_vector_type(4))) float;
using i32x4  = __attribute__((ext_vector_type(4))) int;
using i32x8  = __attribute__((ext_vector_type(8))) int;

__device__ __forceinline__ unsigned short f32_to_bf16(float x) {
    unsigned u = __float_as_uint(x);
    u += 0x7fffu + ((u >> 16) & 1u);   // RTNE
    return (unsigned short)(u >> 16);
}
__device__ __forceinline__ float bf16_to_f32(unsigned short h) {
    return __uint_as_float(((unsigned)h) << 16);
}

// 32-k bf16 plane: [rows][32 bf16] (64 B rows), 2-bit XOR swizzle
__device__ __forceinline__ bf16x8 frag_ld32(const unsigned short* plane, int r, int k2b) {
    int k2 = k2b ^ (((r >> 1) & 3) << 4);
    return *(const bf16x8*)((const char*)plane + r * 64 + k2);
}
// fp8 K=128 plane: [rows][128 fp8] (128 B rows), 3-bit XOR swizzle (16B slot ^= r&7) -> 2-way (free)
__device__ __forceinline__ i32x8 frag_f8k128(const unsigned char* plane, int r, int kg) {
    int s0 = (((kg * 2) ^ (r & 7)) << 4);
    int s1 = (((kg * 2 + 1) ^ (r & 7)) << 4);
    i32x4 lo = *(const i32x4*)(plane + r * 128 + s0);
    i32x4 hi = *(const i32x4*)(plane + r * 128 + s1);
    i32x8 f;
    f[0] = lo[0]; f[1] = lo[1]; f[2] = lo[2]; f[3] = lo[3];
    f[4] = hi[0]; f[5] = hi[1]; f[6] = hi[2]; f[7] = hi[3];
    return f;
}

// ---------------- prep (blocks < N) + wconv (blocks >= N) ----------------
__global__ void prep_kernel(const float* __restrict__ X,
                            const float* __restrict__ W1, const float* __restrict__ W2,
                            const float* __restrict__ W3,
                            unsigned short* __restrict__ Xh, unsigned short* __restrict__ Xl,
                            unsigned char* __restrict__ Xf8,
                            float* __restrict__ sq, float* __restrict__ deg,
                            float* __restrict__ psum, unsigned* __restrict__ tmax,
                            unsigned* __restrict__ cnt,
                            unsigned short* __restrict__ Wt1, unsigned short* __restrict__ Wt2,
                            unsigned short* __restrict__ Wt3) {
    int bid = blockIdx.x;
    if (bid >= N) {   // weight transpose+convert
        int q = bid - N;
        int n = q & (NH - 1), which = q >> 8;
        const float* W = which == 0 ? W1 : (which == 1 ? W2 : W3);
        unsigned short* Wt = which == 0 ? Wt1 : (which == 1 ? Wt2 : Wt3);
        int K = which == 0 ? F : NH;
        int Kp = which == 0 ? K2 : NH;
        for (int k = threadIdx.x; k < Kp; k += 256) {
            float v = (k < K) ? W[(size_t)k * NH + n] : 0.f;
            Wt[(size_t)n * Kp + k] = f32_to_bf16(v);
        }
        return;
    }
    __shared__ float red[256];
    int i = bid;
    int t = threadIdx.x;
    if (t == 0) deg[i] = 1.0f;     // self-loop
    if (i == 0) {
        for (int k = t; k < 3 * NH; k += 256) psum[k] = 0.f;
        if (t == 0) { *tmax = 0u; *cnt = 0u; }
    }
    float s = 0.f;
    // bf16 hi/lo planes + sq
    for (int k = t; k < K2; k += 256) {
        float x = (k < F) ? X[(size_t)i * F + k] : 0.f;
        unsigned short h = f32_to_bf16(x);
        float r = x - bf16_to_f32(h);
        Xh[(size_t)i * K2 + k] = h;
        Xl[(size_t)i * K2 + k] = f32_to_bf16(r);
        s += x * x;
    }
    // fp8 plane: thread t converts the pair (2t, 2t+1)
    {
        int k0 = 2 * t;
        float x0 = (k0 < F) ? X[(size_t)i * F + k0] : 0.f;
        float x1 = (k0 + 1 < F) ? X[(size_t)i * F + k0 + 1] : 0.f;
        int pk = __builtin_amdgcn_cvt_pk_fp8_f32(x0, x1, 0, false);
        *(unsigned short*)(Xf8 + (size_t)i * K2 + k0) = (unsigned short)(pk & 0xffff);
    }
    red[t] = s;
    __syncthreads();
    for (int off = 128; off > 0; off >>= 1) {
        if (t < off) red[t] += red[t + off];
        __syncthreads();
    }
    if (t == 0) sq[i] = red[0];
}

// ---------------- triangular block decode (nb x nb upper-tri) ----------------
__device__ __forceinline__ void tri_decode(int L, int nb, int& bi, int& bj) {
    float a = (float)(2 * nb + 1);
    bi = (int)((a - sqrtf(a * a - 8.0f * (float)L)) * 0.5f);
    if (bi < 0) bi = 0;
    if (bi > nb - 1) bi = nb - 1;
    while (bi > 0 && bi * nb - bi * (bi - 1) / 2 > L) --bi;
    while (bi < nb - 1 && (bi + 1) * nb - (bi + 1) * bi / 2 <= L) ++bi;
    bj = bi + (L - (bi * nb - bi * (bi - 1) / 2));
}

// ---------------- PASS 1: MX-fp8 K=128 distances (scales = 1.0) ----------------
// r12 structure: 128^2 tile, 4 waves (2x2 of 64x64), single 32 KB buffer, 4 K-iters.
__global__ __launch_bounds__(256) void distmax_kernel(const unsigned char* __restrict__ Xf8,
                                                      const float* __restrict__ sq,
                                                      unsigned* __restrict__ tmax,
                                                      float* __restrict__ blockmin) {
    int L = (blockIdx.x % 8) * (TRI2 / 8) + blockIdx.x / 8;  // XCD swizzle (2080%8==0)
    int bi, bj;
    tri_decode(L, NBT, bi, bj);

    __shared__ __align__(16) unsigned char P[2][BT][128];  // A, B fp8 planes = 32 KB
    __shared__ float red[8];

    int tid = threadIdx.x;
    int w = tid >> 6;
    int wm = w >> 1, wn = w & 1;
    int lane = tid & 63;
    int lr = lane & 15;
    int kg = lane >> 4;           // k-group 0..3 (32 fp8 each)

    int gi0 = bi * BT, gj0 = bj * BT;

    // staging: waves 0,1 -> A plane halves; waves 2,3 -> B plane halves
    const unsigned char* srcb = Xf8 + (size_t)((w < 2) ? gi0 : gj0) * K2;
    unsigned char* plane_w = &P[w >> 1][0][0];
    int half = (w & 1) * 64;
    int sr8 = lane >> 3;          // row-in-chunk 0..7
    int sl8 = lane & 7;           // 16-B slot 0..7 within 128-B row

    f32x4 acc[4][4] = {};

    for (int kc = 0; kc < K2; kc += 128) {
        __syncthreads();
#pragma unroll
        for (int c = 0; c < 8; ++c) {
            int row = half + c * 8 + sr8;
            const unsigned char* g = srcb + (size_t)row * K2 + kc + ((sl8 ^ (row & 7)) << 4);
            __builtin_amdgcn_global_load_lds((const void*)g,
                (void*)(plane_w + (half + c * 8) * 128), 16, 0, 0);
        }
        __syncthreads();

        i32x8 af[4], bf[4];
#pragma unroll
        for (int mf = 0; mf < 4; ++mf) af[mf] = frag_f8k128(&P[0][0][0], wm * 64 + mf * 16 + lr, kg);
#pragma unroll
        for (int nf = 0; nf < 4; ++nf) bf[nf] = frag_f8k128(&P[1][0][0], wn * 64 + nf * 16 + lr, kg);
#pragma unroll
        for (int mf = 0; mf < 4; ++mf)
#pragma unroll
            for (int nf = 0; nf < 4; ++nf)
                acc[mf][nf] = __builtin_amdgcn_mfma_scale_f32_16x16x128_f8f6f4(
                    af[mf], bf[nf], acc[mf][nf], 0, 0, 0, 0x7F7F7F7F, 0, 0x7F7F7F7F);
    }

    // epilogue: C/D layout col = lane&15, row = (lane>>4)*4 + reg
    int gi = gi0 + wm * 64, gj = gj0 + wn * 64;
    int rbase = (lane >> 4) << 2;
    float sj[4];
#pragma unroll
    for (int nf = 0; nf < 4; ++nf) sj[nf] = sq[gj + nf * 16 + lr];

    float mmax = 0.f, mmin = 3e38f;
#pragma unroll
    for (int mf = 0; mf < 4; ++mf)
#pragma unroll
        for (int r = 0; r < 4; ++r) {
            int i = gi + mf * 16 + rbase + r;
            float si = sq[i];
#pragma unroll
            for (int nf = 0; nf < 4; ++nf) {
                int j = gj + nf * 16 + lr;
                if (j > i) {
                    float d = si + sj[nf] - 2.0f * acc[mf][nf][r];
                    mmax = fmaxf(mmax, d);
                    mmin = fminf(mmin, d);
                }
            }
        }
    for (int off = 32; off > 0; off >>= 1) {
        mmax = fmaxf(mmax, __shfl_xor(mmax, off, 64));
        mmin = fminf(mmin, __shfl_xor(mmin, off, 64));
    }
    if (lane == 0) { red[w * 2] = mmax; red[w * 2 + 1] = mmin; }
    __syncthreads();
    if (tid == 0) {
        float M = fmaxf(fmaxf(red[0], red[2]), fmaxf(red[4], red[6]));
        float m = fminf(fminf(red[1], red[3]), fminf(red[5], red[7]));
        atomicMax(tmax, __float_as_uint(M));   // d >= 0, bit-compare valid
        blockmin[L] = m;
    }
}

// ---------------- PASS 2: exact (3-plane bf16) edges, only on candidate blocks ----------------
__global__ __launch_bounds__(256) void edges_kernel(const unsigned short* __restrict__ Xh,
                                                    const unsigned short* __restrict__ Xl,
                                                    const float* __restrict__ sq,
                                                    const unsigned* __restrict__ tmax,
                                                    const float* __restrict__ blockmin,
                                                    unsigned* __restrict__ cnt,
                                                    int2* __restrict__ edges,
                                                    float* __restrict__ deg) {
    int L = (blockIdx.x % 8) * (TRI2 / 8) + blockIdx.x / 8;
    float t = 0.5f * __uint_as_float(*tmax);
    if (!(blockmin[L] < t + MARGIN)) return;
    int bi, bj;
    tri_decode(L, NBT, bi, bj);

    __shared__ __align__(16) unsigned short planes[4][BT][32];  // Ah, Al, Bh, Bl = 32 KB

    int tid = threadIdx.x;
    int w = tid >> 6;
    int wm = w >> 1, wn = w & 1;
    int lane = tid & 63;
    int lr = lane & 15;
    int k2b = (lane >> 4) << 4;

    int gi0 = bi * BT, gj0 = bj * BT;

    const unsigned short* srcbase = (w & 1) ? Xl : Xh;
    int grow0 = (w < 2) ? gi0 : gj0;
    unsigned short* plane_w = &planes[w][0][0];

    int srow = lane >> 2;
    int sk2 = ((lane & 3) << 4);

    f32x4 acc[4][4] = {};

    for (int kc = 0; kc < K2; kc += 32) {
        __syncthreads();
#pragma unroll
        for (int c = 0; c < 8; ++c) {
            int row = c * 16 + srow;
            int k2 = sk2 ^ (((row >> 1) & 3) << 4);
            const char* g = (const char*)(srcbase + (size_t)(grow0 + row) * K2 + kc) + k2;
            __builtin_amdgcn_global_load_lds((const void*)g, (void*)((char*)plane_w + c * 1024), 16, 0, 0);
        }
        __syncthreads();

        bf16x8 ahf[4], alf[4], bhf[4], blf[4];
#pragma unroll
        for (int mf = 0; mf < 4; ++mf) {
            int r = wm * 64 + mf * 16 + lr;
            ahf[mf] = frag_ld32(&planes[0][0][0], r, k2b);
            alf[mf] = frag_ld32(&planes[1][0][0], r, k2b);
        }
#pragma unroll
        for (int nf = 0; nf < 4; ++nf) {
            int r = wn * 64 + nf * 16 + lr;
            bhf[nf] = frag_ld32(&planes[2][0][0], r, k2b);
            blf[nf] = frag_ld32(&planes[3][0][0], r, k2b);
        }
#pragma unroll
        for (int mf = 0; mf < 4; ++mf)
#pragma unroll
            for (int nf = 0; nf < 4; ++nf) {
                acc[mf][nf] = __builtin_amdgcn_mfma_f32_16x16x32_bf16(ahf[mf], bhf[nf], acc[mf][nf], 0, 0, 0);
                acc[mf][nf] = __builtin_amdgcn_mfma_f32_16x16x32_bf16(ahf[mf], blf[nf], acc[mf][nf], 0, 0, 0);
                acc[mf][nf] = __builtin_amdgcn_mfma_f32_16x16x32_bf16(alf[mf], bhf[nf], acc[mf][nf], 0, 0, 0);
            }
    }

    int gi = gi0 + wm * 64, gj = gj0 + wn * 64;
    int rbase = (lane >> 4) << 2;
    float sj[4];
#pragma unroll
    for (int nf = 0; nf < 4; ++nf) sj[nf] = sq[gj + nf * 16 + lr];

#pragma unroll
    for (int mf = 0; mf < 4; ++mf)
#pragma unroll
        for (int r = 0; r < 4; ++r) {
            int i = gi + mf * 16 + rbase + r;
            float si = sq[i];
#pragma unroll
            for (int nf = 0; nf < 4; ++nf) {
                int j = gj + nf * 16 + lr;
                if (j > i) {
                    float d = si + sj[nf] - 2.0f * acc[mf][nf][r];
                    if (d < t) {
                        unsigned p = atomicAdd(cnt, 1u);
                        if (p < (unsigned)CAP) edges[p] = make_int2(i, j);
                        atomicAdd(&deg[j], 1.0f);
                    }
                }
            }
        }
}

// ---------------- MFMA GEMM 64x64 + fused self-agg/bias/relu/pool epilogue ----------------
__global__ __launch_bounds__(256) void gemm_fused_kernel(const unsigned short* __restrict__ A,
                                                         const unsigned short* __restrict__ Wt,
                                                         const float* __restrict__ deg,
                                                         const float* __restrict__ b,
                                                         float* __restrict__ H,
                                                         unsigned short* __restrict__ Xbo,
                                                         float* __restrict__ psum, int Kp) {
    __shared__ __align__(16) unsigned short P[2][2][64][32];  // [buf][A/B] = 16 KB
    int bm = blockIdx.x, bn = blockIdx.y;
    int tid = threadIdx.x;
    int w = tid >> 6;
    int wm = w >> 1, wn = w & 1;      // 2x2 waves, 32x32 each
    int lane = tid & 63;
    int lr = lane & 15;
    int k2b = (lane >> 4) << 4;

    int gm0 = bm * 64, gn0 = bn * 64;

    const unsigned short* srcbase = (w < 2) ? A + (size_t)gm0 * Kp : Wt + (size_t)gn0 * Kp;
    int pidx = (w < 2) ? 0 : 1;
    int rowbase = (w & 1) * 32;
    int sr = lane >> 2;               // 0..15
    int ss = lane & 3;                // 0..3
    int kb = ((ss ^ ((sr >> 1) & 3)) << 4);

    auto STAGE = [&](int buf, int kc) {
        char* dst = (char*)&P[buf][pidx][0][0] + rowbase * 64;
#pragma unroll
        for (int c = 0; c < 2; ++c) {
            int row = rowbase + c * 16 + sr;
            const char* g = (const char*)srcbase + ((size_t)row * Kp + kc) * 2 + kb;
            __builtin_amdgcn_global_load_lds((const void*)g, (void*)(dst + c * 1024), 16, 0, 0);
        }
    };

    f32x4 acc[2][2] = {};

    int nt = Kp / 32;
    STAGE(0, 0);
    STAGE(1, 32);
    for (int t = 0; t < nt; ++t) {
        const int c = t & 1;
        if (t < nt - 1) { asm volatile("s_waitcnt vmcnt(2)" ::: "memory"); }
        else            { asm volatile("s_waitcnt vmcnt(0)" ::: "memory"); }
        __builtin_amdgcn_sched_barrier(0);
        __builtin_amdgcn_s_barrier();
        const unsigned short* pA = &P[c][0][0][0];
        const unsigned short* pB = &P[c][1][0][0];
        bf16x8 af[2], bfr[2];
#pragma unroll
        for (int mf = 0; mf < 2; ++mf) af[mf] = frag_ld32(pA, wm * 32 + mf * 16 + lr, k2b);
#pragma unroll
        for (int nf = 0; nf < 2; ++nf) bfr[nf] = frag_ld32(pB, wn * 32 + nf * 16 + lr, k2b);
        __builtin_amdgcn_s_setprio(1);
#pragma unroll
        for (int mf = 0; mf < 2; ++mf)
#pragma unroll
            for (int nf = 0; nf < 2; ++nf)
                acc[mf][nf] = __builtin_amdgcn_mfma_f32_16x16x32_bf16(af[mf], bfr[nf], acc[mf][nf], 0, 0, 0);
        __builtin_amdgcn_s_setprio(0);
        asm volatile("s_waitcnt lgkmcnt(0)" ::: "memory");
        __builtin_amdgcn_sched_barrier(0);
        __builtin_amdgcn_s_barrier();
        if (t + 2 < nt) STAGE(c, (t + 2) * 32);
    }

    // fused epilogue: H raw, Xb = bf16(relu(H/deg + b)), psum += column sums
    int rbase = (lane >> 4) << 2;
    float bias[2], ps[2] = {0.f, 0.f};
    int col[2];
#pragma unroll
    for (int nf = 0; nf < 2; ++nf) { col[nf] = gn0 + wn * 32 + nf * 16 + lr; bias[nf] = b[col[nf]]; }
#pragma unroll
    for (int mf = 0; mf < 2; ++mf)
#pragma unroll
        for (int r = 0; r < 4; ++r) {
            int row = gm0 + wm * 32 + mf * 16 + rbase + r;
            float dv = deg[row];
#pragma unroll
            for (int nf = 0; nf < 2; ++nf) {
                float hraw = acc[mf][nf][r];
                size_t idx = (size_t)row * NH + col[nf];
                H[idx] = hraw;
                float v = fmaxf(hraw / dv + bias[nf], 0.f);
                Xbo[idx] = f32_to_bf16(v);
                ps[nf] += v;
            }
        }
#pragma unroll
    for (int nf = 0; nf < 2; ++nf) {
        ps[nf] += __shfl_xor(ps[nf], 16, 64);
        ps[nf] += __shfl_xor(ps[nf], 32, 64);
        if (lane < 16) atomicAdd(&psum[col[nf]], ps[nf]);
    }
}

// ---------------- edge fixup (+ fused finalize on the last layer) ----------------
__global__ void fixup_kernel(const float* __restrict__ H, const float* __restrict__ deg,
                             const int2* __restrict__ edges, const unsigned* __restrict__ cnt,
                             const float* __restrict__ b, unsigned short* __restrict__ Xbo,
                             float* __restrict__ psum, int layer, float* __restrict__ out) {
    int f = threadIdx.x;
    unsigned n = *cnt;
    if (n > 4096u) n = 4096u;
    float bias = b[f];
    float dpsum = 0.f;
    for (unsigned e = 0; e < n; ++e) {
        int j = edges[e].y;
        bool dup = false;
        for (unsigned e2 = 0; e2 < e; ++e2)
            if (edges[e2].y == j) { dup = true; break; }
        if (dup) continue;
        float base = H[(size_t)j * NH + f] / deg[j] + bias;   // matches gemm epilogue math
        float accv = base;
        for (unsigned e2 = e; e2 < n; ++e2)
            if (edges[e2].y == j) {
                int i = edges[e2].x;
                accv += (1.0f / sqrtf(deg[i])) * (1.0f / sqrtf(deg[j])) * H[(size_t)i * NH + f];
            }
        float oldv = fmaxf(base, 0.f);
        float newv = fmaxf(accv, 0.f);
        dpsum += newv - oldv;
        Xbo[(size_t)j * NH + f] = f32_to_bf16(newv);
    }
    psum[layer * NH + f] += dpsum;   // single block; thread f owns psum[.][f]
    if (out) {
        float p = (psum[f] + psum[NH + f] + psum[2 * NH + f]) * (1.0f / (float)N);
        out[f] = p;
        out[NH + f] = p;
    }
}

static inline size_t align_up(size_t x, size_t a) { return (x + a - 1) & ~(a - 1); }

extern "C" void kernel_launch(void* const* d_in, const int* in_sizes, int n_in,
                              void* d_out, int out_size, void* d_ws, size_t ws_size,
                              hipStream_t stream) {
    const float* feature = (const float*)d_in[0];
    const float* W1 = (const float*)d_in[1];
    const float* b1 = (const float*)d_in[2];
    const float* W2 = (const float*)d_in[3];
    const float* b2 = (const float*)d_in[4];
    const float* W3 = (const float*)d_in[5];
    const float* b3 = (const float*)d_in[6];
    float* out = (float*)d_out;

    char* w = (char*)d_ws;
    size_t off = 0;
    float* sq = (float*)(w + off);         off += (size_t)N * 4;
    float* deg = (float*)(w + off);        off += (size_t)N * 4;
    float* psum = (float*)(w + off);       off += 3 * NH * 4;
    unsigned* tmax = (unsigned*)(w + off); off += 4;
    unsigned* cnt = (unsigned*)(w + off);  off += 4;
    off = align_up(off, 256);
    float* blockmin = (float*)(w + off);   off += (size_t)TRI2 * 4;
    off = align_up(off, 256);
    int2* edges = (int2*)(w + off);        off += (size_t)CAP * 8;
    off = align_up(off, 256);
    float* H = (float*)(w + off);          off += (size_t)N * NH * 4;
    off = align_up(off, 256);
    unsigned short* Xh = (unsigned short*)(w + off);  off += (size_t)N * K2 * 2;
    unsigned short* Xl = (unsigned short*)(w + off);  off += (size_t)N * K2 * 2;
    unsigned char* Xf8 = (unsigned char*)(w + off);   off += (size_t)N * K2;
    unsigned short* Wt1 = (unsigned short*)(w + off); off += (size_t)NH * K2 * 2;
    unsigned short* Wt2 = (unsigned short*)(w + off); off += (size_t)NH * NH * 2;
    unsigned short* Wt3 = (unsigned short*)(w + off); off += (size_t)NH * NH * 2;
    unsigned short* Xb1 = (unsigned short*)(w + off); off += (size_t)N * NH * 2;
    unsigned short* Xb2 = (unsigned short*)(w + off); off += (size_t)N * NH * 2;

    prep_kernel<<<N + 3 * NH, 256, 0, stream>>>(feature, W1, W2, W3, Xh, Xl, Xf8, sq, deg,
                                                psum, tmax, cnt, Wt1, Wt2, Wt3);
    distmax_kernel<<<TRI2, 256, 0, stream>>>(Xf8, sq, tmax, blockmin);
    edges_kernel<<<TRI2, 256, 0, stream>>>(Xh, Xl, sq, tmax, blockmin, cnt, edges, deg);

    dim3 ggrid(N / 64, NH / 64);
    // layer 1: A = Xh (bf16 hi plane, K=512) -> Xb1
    gemm_fused_kernel<<<ggrid, 256, 0, stream>>>(Xh, Wt1, deg, b1, H, Xb1, psum, K2);
    fixup_kernel<<<1, NH, 0, stream>>>(H, deg, edges, cnt, b1, Xb1, psum, 0, nullptr);
    // layer 2: A = Xb1 -> Xb2
    gemm_fused_kernel<<<ggrid, 256, 0, stream>>>(Xb1, Wt2, deg, b2, H, Xb2, psum + NH, NH);
    fixup_kernel<<<1, NH, 0, stream>>>(H, deg, edges, cnt, b2, Xb2, psum, 1, nullptr);
    // layer 3: A = Xb2 -> Xb1  (fixup also finalizes the output)
    gemm_fused_kernel<<<ggrid, 256, 0, stream>>>(Xb2, Wt3, deg, b3, H, Xb1, psum + 2 * NH, NH);
    fixup_kernel<<<1, NH, 0, stream>>>(H, deg, edges, cnt, b3, Xb1, psum, 2, out);
}

// Round 15
// 127.978 us; speedup vs baseline: 1.2048x; 1.2048x over previous
//
#include <hip/hip_runtime.h>

#define N 8192
#define F 500
#define K2 512                        // F padded to MFMA-friendly K
#define NH 256
#define CAP (1 << 17)
#define BT 128                        // dist tile
#define NBT (N / BT)                  // 64
#define TRI2 (NBT * (NBT + 1) / 2)    // 2080 (%8==0)
#define MARGIN 16.0f                  // |d_fp8 - d_exact| safety bound for pass-2 filter

using bf16x8 = __attribute__((ext_vector_type(8))) short;
using f32x4  = __attribute__((ext_vector_type(4))) float;

__device__ __forceinline__ unsigned short f32_to_bf16(float x) {
    unsigned u = __float_as_uint(x);
    u += 0x7fffu + ((u >> 16) & 1u);   // RTNE
    return (unsigned short)(u >> 16);
}
__device__ __forceinline__ float bf16_to_f32(unsigned short h) {
    return __uint_as_float(((unsigned)h) << 16);
}

// 32-k bf16 plane: [rows][32 bf16] (64 B rows), 2-bit XOR swizzle
__device__ __forceinline__ bf16x8 frag_ld32(const unsigned short* plane, int r, int k2b) {
    int k2 = k2b ^ (((r >> 1) & 3) << 4);
    return *(const bf16x8*)((const char*)plane + r * 64 + k2);
}
// fp8 plane: [rows][64 fp8] (64 B rows), XOR 16-B slot with (r>>1)&3 -> 2-way (free)
__device__ __forceinline__ long frag_f8(const unsigned char* plane, int r, int b) {
    int sw = ((((b >> 4) ^ ((r >> 1) & 3)) << 4) | (b & 15));
    return *(const long*)(plane + r * 64 + sw);
}

// ---------------- prep (blocks < N) + wconv (blocks >= N) ----------------
// single pass: thread t owns elements (2t, 2t+1) of row i for all outputs
__global__ void prep_kernel(const float* __restrict__ X,
                            const float* __restrict__ W1, const float* __restrict__ W2,
                            const float* __restrict__ W3,
                            unsigned short* __restrict__ Xh, unsigned short* __restrict__ Xl,
                            unsigned char* __restrict__ Xf8,
                            float* __restrict__ sq, float* __restrict__ deg,
                            float* __restrict__ psum, unsigned* __restrict__ tmax,
                            unsigned* __restrict__ cnt,
                            unsigned short* __restrict__ Wt1, unsigned short* __restrict__ Wt2,
                            unsigned short* __restrict__ Wt3) {
    int bid = blockIdx.x;
    if (bid >= N) {   // weight transpose+convert
        int q = bid - N;
        int n = q & (NH - 1), which = q >> 8;
        const float* W = which == 0 ? W1 : (which == 1 ? W2 : W3);
        unsigned short* Wt = which == 0 ? Wt1 : (which == 1 ? Wt2 : Wt3);
        int K = which == 0 ? F : NH;
        int Kp = which == 0 ? K2 : NH;
        for (int k = threadIdx.x; k < Kp; k += 256) {
            float v = (k < K) ? W[(size_t)k * NH + n] : 0.f;
            Wt[(size_t)n * Kp + k] = f32_to_bf16(v);
        }
        return;
    }
    __shared__ float red[256];
    int i = bid;
    int t = threadIdx.x;
    if (t == 0) deg[i] = 1.0f;     // self-loop
    if (i == 0) {
        for (int k = t; k < 3 * NH; k += 256) psum[k] = 0.f;
        if (t == 0) { *tmax = 0u; *cnt = 0u; }
    }
    int k0 = 2 * t;
    float x0 = 0.f, x1 = 0.f;
    if (k0 + 1 < F) {   // F=500 even: t<250 loads a full float2
        float2 v = *(const float2*)(X + (size_t)i * F + k0);
        x0 = v.x; x1 = v.y;
    }
    unsigned short h0 = f32_to_bf16(x0), h1 = f32_to_bf16(x1);
    float r0 = x0 - bf16_to_f32(h0), r1 = x1 - bf16_to_f32(h1);
    *(unsigned*)(Xh + (size_t)i * K2 + k0) = (unsigned)h0 | ((unsigned)h1 << 16);
    *(unsigned*)(Xl + (size_t)i * K2 + k0) =
        (unsigned)f32_to_bf16(r0) | ((unsigned)f32_to_bf16(r1) << 16);
    int pk = __builtin_amdgcn_cvt_pk_fp8_f32(x0, x1, 0, false);
    *(unsigned short*)(Xf8 + (size_t)i * K2 + k0) = (unsigned short)(pk & 0xffff);

    red[t] = x0 * x0 + x1 * x1;
    __syncthreads();
    for (int off = 128; off > 0; off >>= 1) {
        if (t < off) red[t] += red[t + off];
        __syncthreads();
    }
    if (t == 0) sq[i] = red[0];
}

// ---------------- triangular block decode (nb x nb upper-tri) ----------------
__device__ __forceinline__ void tri_decode(int L, int nb, int& bi, int& bj) {
    float a = (float)(2 * nb + 1);
    bi = (int)((a - sqrtf(a * a - 8.0f * (float)L)) * 0.5f);
    if (bi < 0) bi = 0;
    if (bi > nb - 1) bi = nb - 1;
    while (bi > 0 && bi * nb - bi * (bi - 1) / 2 > L) --bi;
    while (bi < nb - 1 && (bi + 1) * nb - (bi + 1) * bi / 2 <= L) ++bi;
    bj = bi + (L - (bi * nb - bi * (bi - 1) / 2));
}

// ---------------- PASS 1: fp8 distances, r12 structure + double buffer ----------------
// 128^2 tile, 4 waves (2x2 of 64x64), KS=64 fp8, dbuf 32 KB, one barrier per iter.
// NO launch_bounds min-waves (r11 lesson: it forced accumulator spills).
__global__ __launch_bounds__(256) void distmax_kernel(const unsigned char* __restrict__ Xf8,
                                                      const float* __restrict__ sq,
                                                      unsigned* __restrict__ tmax,
                                                      float* __restrict__ blockmin) {
    int L = (blockIdx.x % 8) * (TRI2 / 8) + blockIdx.x / 8;  // XCD swizzle (2080%8==0)
    int bi, bj;
    tri_decode(L, NBT, bi, bj);

    __shared__ __align__(16) unsigned char P[2][2][BT][64];  // [buf][A/B] fp8 = 32 KB
    __shared__ float red[8];

    int tid = threadIdx.x;
    int w = tid >> 6;
    int wm = w >> 1, wn = w & 1;
    int lane = tid & 63;
    int lr = lane & 15;

    int gi0 = bi * BT, gj0 = bj * BT;

    // staging: waves 0,1 -> A plane halves; waves 2,3 -> B plane halves
    const unsigned char* srcb = Xf8 + (size_t)((w < 2) ? gi0 : gj0) * K2;
    int pidx = w >> 1;
    int half = (w & 1) * 64;
    int srw = lane >> 2;          // row-in-chunk 0..15
    int slot = lane & 3;          // 16-B slot 0..3

    auto STAGE = [&](int buf, int kc) {   // 4 global_load_lds per wave
        unsigned char* plane_w = &P[buf][pidx][0][0];
#pragma unroll
        for (int c = 0; c < 4; ++c) {
            int row = half + c * 16 + srw;
            const unsigned char* g = srcb + (size_t)row * K2 + kc
                                   + ((slot ^ ((row >> 1) & 3)) << 4);
            __builtin_amdgcn_global_load_lds((const void*)g,
                (void*)(plane_w + (half + c * 16) * 64), 16, 0, 0);
        }
    };

    f32x4 acc[4][4] = {};

    STAGE(0, 0);
    __syncthreads();              // buf0 staged
#pragma unroll
    for (int t = 0; t < K2 / 64; ++t) {
        const int c = t & 1;
        if (t + 1 < K2 / 64) STAGE(c ^ 1, (t + 1) * 64);  // prefetch next into free buf
#pragma unroll
        for (int ks = 0; ks < 2; ++ks) {
            int b = ks * 32 + ((lane >> 4) << 3);
            long af[4], bf[4];
#pragma unroll
            for (int mf = 0; mf < 4; ++mf) af[mf] = frag_f8(&P[c][0][0][0], wm * 64 + mf * 16 + lr, b);
#pragma unroll
            for (int nf = 0; nf < 4; ++nf) bf[nf] = frag_f8(&P[c][1][0][0], wn * 64 + nf * 16 + lr, b);
#pragma unroll
            for (int mf = 0; mf < 4; ++mf)
#pragma unroll
                for (int nf = 0; nf < 4; ++nf)
                    acc[mf][nf] = __builtin_amdgcn_mfma_f32_16x16x32_fp8_fp8(af[mf], bf[nf], acc[mf][nf], 0, 0, 0);
        }
        __syncthreads();   // all waves done reading buf c; prefetch drained -> buf c^1 ready
    }

    // epilogue: C/D layout col = lane&15, row = (lane>>4)*4 + reg
    int gi = gi0 + wm * 64, gj = gj0 + wn * 64;
    int rbase = (lane >> 4) << 2;
    float sj[4];
#pragma unroll
    for (int nf = 0; nf < 4; ++nf) sj[nf] = sq[gj + nf * 16 + lr];

    float mmax = 0.f, mmin = 3e38f;
#pragma unroll
    for (int mf = 0; mf < 4; ++mf)
#pragma unroll
        for (int r = 0; r < 4; ++r) {
            int i = gi + mf * 16 + rbase + r;
            float si = sq[i];
#pragma unroll
            for (int nf = 0; nf < 4; ++nf) {
                int j = gj + nf * 16 + lr;
                if (j > i) {
                    float d = si + sj[nf] - 2.0f * acc[mf][nf][r];
                    mmax = fmaxf(mmax, d);
                    mmin = fminf(mmin, d);
                }
            }
        }
    for (int off = 32; off > 0; off >>= 1) {
        mmax = fmaxf(mmax, __shfl_xor(mmax, off, 64));
        mmin = fminf(mmin, __shfl_xor(mmin, off, 64));
    }
    if (lane == 0) { red[w * 2] = mmax; red[w * 2 + 1] = mmin; }
    __syncthreads();
    if (tid == 0) {
        float M = fmaxf(fmaxf(red[0], red[2]), fmaxf(red[4], red[6]));
        float m = fminf(fminf(red[1], red[3]), fminf(red[5], red[7]));
        atomicMax(tmax, __float_as_uint(M));   // d >= 0, bit-compare valid
        blockmin[L] = m;
    }
}

// ---------------- PASS 2: exact (3-plane bf16) edges, only on candidate blocks ----------------
__global__ __launch_bounds__(256) void edges_kernel(const unsigned short* __restrict__ Xh,
                                                    const unsigned short* __restrict__ Xl,
                                                    const float* __restrict__ sq,
                                                    const unsigned* __restrict__ tmax,
                                                    const float* __restrict__ blockmin,
                                                    unsigned* __restrict__ cnt,
                                                    int2* __restrict__ edges,
                                                    float* __restrict__ deg) {
    int L = (blockIdx.x % 8) * (TRI2 / 8) + blockIdx.x / 8;
    float t = 0.5f * __uint_as_float(*tmax);
    if (!(blockmin[L] < t + MARGIN)) return;
    int bi, bj;
    tri_decode(L, NBT, bi, bj);

    __shared__ __align__(16) unsigned short planes[4][BT][32];  // Ah, Al, Bh, Bl = 32 KB

    int tid = threadIdx.x;
    int w = tid >> 6;
    int wm = w >> 1, wn = w & 1;
    int lane = tid & 63;
    int lr = lane & 15;
    int k2b = (lane >> 4) << 4;

    int gi0 = bi * BT, gj0 = bj * BT;

    const unsigned short* srcbase = (w & 1) ? Xl : Xh;
    int grow0 = (w < 2) ? gi0 : gj0;
    unsigned short* plane_w = &planes[w][0][0];

    int srow = lane >> 2;
    int sk2 = ((lane & 3) << 4);

    f32x4 acc[4][4] = {};

    for (int kc = 0; kc < K2; kc += 32) {
        __syncthreads();
#pragma unroll
        for (int c = 0; c < 8; ++c) {
            int row = c * 16 + srow;
            int k2 = sk2 ^ (((row >> 1) & 3) << 4);
            const char* g = (const char*)(srcbase + (size_t)(grow0 + row) * K2 + kc) + k2;
            __builtin_amdgcn_global_load_lds((const void*)g, (void*)((char*)plane_w + c * 1024), 16, 0, 0);
        }
        __syncthreads();

        bf16x8 ahf[4], alf[4], bhf[4], blf[4];
#pragma unroll
        for (int mf = 0; mf < 4; ++mf) {
            int r = wm * 64 + mf * 16 + lr;
            ahf[mf] = frag_ld32(&planes[0][0][0], r, k2b);
            alf[mf] = frag_ld32(&planes[1][0][0], r, k2b);
        }
#pragma unroll
        for (int nf = 0; nf < 4; ++nf) {
            int r = wn * 64 + nf * 16 + lr;
            bhf[nf] = frag_ld32(&planes[2][0][0], r, k2b);
            blf[nf] = frag_ld32(&planes[3][0][0], r, k2b);
        }
#pragma unroll
        for (int mf = 0; mf < 4; ++mf)
#pragma unroll
            for (int nf = 0; nf < 4; ++nf) {
                acc[mf][nf] = __builtin_amdgcn_mfma_f32_16x16x32_bf16(ahf[mf], bhf[nf], acc[mf][nf], 0, 0, 0);
                acc[mf][nf] = __builtin_amdgcn_mfma_f32_16x16x32_bf16(ahf[mf], blf[nf], acc[mf][nf], 0, 0, 0);
                acc[mf][nf] = __builtin_amdgcn_mfma_f32_16x16x32_bf16(alf[mf], bhf[nf], acc[mf][nf], 0, 0, 0);
            }
    }

    int gi = gi0 + wm * 64, gj = gj0 + wn * 64;
    int rbase = (lane >> 4) << 2;
    float sj[4];
#pragma unroll
    for (int nf = 0; nf < 4; ++nf) sj[nf] = sq[gj + nf * 16 + lr];

#pragma unroll
    for (int mf = 0; mf < 4; ++mf)
#pragma unroll
        for (int r = 0; r < 4; ++r) {
            int i = gi + mf * 16 + rbase + r;
            float si = sq[i];
#pragma unroll
            for (int nf = 0; nf < 4; ++nf) {
                int j = gj + nf * 16 + lr;
                if (j > i) {
                    float d = si + sj[nf] - 2.0f * acc[mf][nf][r];
                    if (d < t) {
                        unsigned p = atomicAdd(cnt, 1u);
                        if (p < (unsigned)CAP) edges[p] = make_int2(i, j);
                        atomicAdd(&deg[j], 1.0f);
                    }
                }
            }
        }
}

// ---------------- MFMA GEMM 64x64 + fused self-agg/bias/relu/pool epilogue ----------------
__global__ __launch_bounds__(256) void gemm_fused_kernel(const unsigned short* __restrict__ A,
                                                         const unsigned short* __restrict__ Wt,
                                                         const float* __restrict__ deg,
                                                         const float* __restrict__ b,
                                                         float* __restrict__ H,
                                                         unsigned short* __restrict__ Xbo,
                                                         float* __restrict__ psum, int Kp) {
    __shared__ __align__(16) unsigned short P[2][2][64][32];  // [buf][A/B] = 16 KB
    int bm = blockIdx.x, bn = blockIdx.y;
    int tid = threadIdx.x;
    int w = tid >> 6;
    int wm = w >> 1, wn = w & 1;      // 2x2 waves, 32x32 each
    int lane = tid & 63;
    int lr = lane & 15;
    int k2b = (lane >> 4) << 4;

    int gm0 = bm * 64, gn0 = bn * 64;

    const unsigned short* srcbase = (w < 2) ? A + (size_t)gm0 * Kp : Wt + (size_t)gn0 * Kp;
    int pidx = (w < 2) ? 0 : 1;
    int rowbase = (w & 1) * 32;
    int sr = lane >> 2;               // 0..15
    int ss = lane & 3;                // 0..3
    int kb = ((ss ^ ((sr >> 1) & 3)) << 4);

    auto STAGE = [&](int buf, int kc) {
        char* dst = (char*)&P[buf][pidx][0][0] + rowbase * 64;
#pragma unroll
        for (int c = 0; c < 2; ++c) {
            int row = rowbase + c * 16 + sr;
            const char* g = (const char*)srcbase + ((size_t)row * Kp + kc) * 2 + kb;
            __builtin_amdgcn_global_load_lds((const void*)g, (void*)(dst + c * 1024), 16, 0, 0);
        }
    };

    f32x4 acc[2][2] = {};

    int nt = Kp / 32;
    STAGE(0, 0);
    STAGE(1, 32);
    for (int t = 0; t < nt; ++t) {
        const int c = t & 1;
        if (t < nt - 1) { asm volatile("s_waitcnt vmcnt(2)" ::: "memory"); }
        else            { asm volatile("s_waitcnt vmcnt(0)" ::: "memory"); }
        __builtin_amdgcn_sched_barrier(0);
        __builtin_amdgcn_s_barrier();
        const unsigned short* pA = &P[c][0][0][0];
        const unsigned short* pB = &P[c][1][0][0];
        bf16x8 af[2], bfr[2];
#pragma unroll
        for (int mf = 0; mf < 2; ++mf) af[mf] = frag_ld32(pA, wm * 32 + mf * 16 + lr, k2b);
#pragma unroll
        for (int nf = 0; nf < 2; ++nf) bfr[nf] = frag_ld32(pB, wn * 32 + nf * 16 + lr, k2b);
        __builtin_amdgcn_s_setprio(1);
#pragma unroll
        for (int mf = 0; mf < 2; ++mf)
#pragma unroll
            for (int nf = 0; nf < 2; ++nf)
                acc[mf][nf] = __builtin_amdgcn_mfma_f32_16x16x32_bf16(af[mf], bfr[nf], acc[mf][nf], 0, 0, 0);
        __builtin_amdgcn_s_setprio(0);
        asm volatile("s_waitcnt lgkmcnt(0)" ::: "memory");
        __builtin_amdgcn_sched_barrier(0);
        __builtin_amdgcn_s_barrier();
        if (t + 2 < nt) STAGE(c, (t + 2) * 32);
    }

    // fused epilogue: H raw, Xb = bf16(relu(H/deg + b)), psum += column sums
    int rbase = (lane >> 4) << 2;
    float bias[2], ps[2] = {0.f, 0.f};
    int col[2];
#pragma unroll
    for (int nf = 0; nf < 2; ++nf) { col[nf] = gn0 + wn * 32 + nf * 16 + lr; bias[nf] = b[col[nf]]; }
#pragma unroll
    for (int mf = 0; mf < 2; ++mf)
#pragma unroll
        for (int r = 0; r < 4; ++r) {
            int row = gm0 + wm * 32 + mf * 16 + rbase + r;
            float dv = deg[row];
#pragma unroll
            for (int nf = 0; nf < 2; ++nf) {
                float hraw = acc[mf][nf][r];
                size_t idx = (size_t)row * NH + col[nf];
                H[idx] = hraw;
                float v = fmaxf(hraw / dv + bias[nf], 0.f);
                Xbo[idx] = f32_to_bf16(v);
                ps[nf] += v;
            }
        }
#pragma unroll
    for (int nf = 0; nf < 2; ++nf) {
        ps[nf] += __shfl_xor(ps[nf], 16, 64);
        ps[nf] += __shfl_xor(ps[nf], 32, 64);
        if (lane < 16) atomicAdd(&psum[col[nf]], ps[nf]);
    }
}

// ---------------- edge fixup (+ fused finalize on the last layer) ----------------
__global__ void fixup_kernel(const float* __restrict__ H, const float* __restrict__ deg,
                             const int2* __restrict__ edges, const unsigned* __restrict__ cnt,
                             const float* __restrict__ b, unsigned short* __restrict__ Xbo,
                             float* __restrict__ psum, int layer, float* __restrict__ out) {
    int f = threadIdx.x;
    unsigned n = *cnt;
    if (n > 4096u) n = 4096u;
    float bias = b[f];
    float dpsum = 0.f;
    for (unsigned e = 0; e < n; ++e) {
        int j = edges[e].y;
        bool dup = false;
        for (unsigned e2 = 0; e2 < e; ++e2)
            if (edges[e2].y == j) { dup = true; break; }
        if (dup) continue;
        float base = H[(size_t)j * NH + f] / deg[j] + bias;   // matches gemm epilogue math
        float accv = base;
        for (unsigned e2 = e; e2 < n; ++e2)
            if (edges[e2].y == j) {
                int i = edges[e2].x;
                accv += (1.0f / sqrtf(deg[i])) * (1.0f / sqrtf(deg[j])) * H[(size_t)i * NH + f];
            }
        float oldv = fmaxf(base, 0.f);
        float newv = fmaxf(accv, 0.f);
        dpsum += newv - oldv;
        Xbo[(size_t)j * NH + f] = f32_to_bf16(newv);
    }
    psum[layer * NH + f] += dpsum;   // single block; thread f owns psum[.][f]
    if (out) {
        float p = (psum[f] + psum[NH + f] + psum[2 * NH + f]) * (1.0f / (float)N);
        out[f] = p;
        out[NH + f] = p;
    }
}

static inline size_t align_up(size_t x, size_t a) { return (x + a - 1) & ~(a - 1); }

extern "C" void kernel_launch(void* const* d_in, const int* in_sizes, int n_in,
                              void* d_out, int out_size, void* d_ws, size_t ws_size,
                              hipStream_t stream) {
    const float* feature = (const float*)d_in[0];
    const float* W1 = (const float*)d_in[1];
    const float* b1 = (const float*)d_in[2];
    const float* W2 = (const float*)d_in[3];
    const float* b2 = (const float*)d_in[4];
    const float* W3 = (const float*)d_in[5];
    const float* b3 = (const float*)d_in[6];
    float* out = (float*)d_out;

    char* w = (char*)d_ws;
    size_t off = 0;
    float* sq = (float*)(w + off);         off += (size_t)N * 4;
    float* deg = (float*)(w + off);        off += (size_t)N * 4;
    float* psum = (float*)(w + off);       off += 3 * NH * 4;
    unsigned* tmax = (unsigned*)(w + off); off += 4;
    unsigned* cnt = (unsigned*)(w + off);  off += 4;
    off = align_up(off, 256);
    float* blockmin = (float*)(w + off);   off += (size_t)TRI2 * 4;
    off = align_up(off, 256);
    int2* edges = (int2*)(w + off);        off += (size_t)CAP * 8;
    off = align_up(off, 256);
    float* H = (float*)(w + off);          off += (size_t)N * NH * 4;
    off = align_up(off, 256);
    unsigned short* Xh = (unsigned short*)(w + off);  off += (size_t)N * K2 * 2;
    unsigned short* Xl = (unsigned short*)(w + off);  off += (size_t)N * K2 * 2;
    unsigned char* Xf8 = (unsigned char*)(w + off);   off += (size_t)N * K2;
    unsigned short* Wt1 = (unsigned short*)(w + off); off += (size_t)NH * K2 * 2;
    unsigned short* Wt2 = (unsigned short*)(w + off); off += (size_t)NH * NH * 2;
    unsigned short* Wt3 = (unsigned short*)(w + off); off += (size_t)NH * NH * 2;
    unsigned short* Xb1 = (unsigned short*)(w + off); off += (size_t)N * NH * 2;
    unsigned short* Xb2 = (unsigned short*)(w + off); off += (size_t)N * NH * 2;

    prep_kernel<<<N + 3 * NH, 256, 0, stream>>>(feature, W1, W2, W3, Xh, Xl, Xf8, sq, deg,
                                                psum, tmax, cnt, Wt1, Wt2, Wt3);
    distmax_kernel<<<TRI2, 256, 0, stream>>>(Xf8, sq, tmax, blockmin);
    edges_kernel<<<TRI2, 256, 0, stream>>>(Xh, Xl, sq, tmax, blockmin, cnt, edges, deg);

    dim3 ggrid(N / 64, NH / 64);
    // layer 1: A = Xh (bf16 hi plane, K=512) -> Xb1
    gemm_fused_kernel<<<ggrid, 256, 0, stream>>>(Xh, Wt1, deg, b1, H, Xb1, psum, K2);
    fixup_kernel<<<1, NH, 0, stream>>>(H, deg, edges, cnt, b1, Xb1, psum, 0, nullptr);
    // layer 2: A = Xb1 -> Xb2
    gemm_fused_kernel<<<ggrid, 256, 0, stream>>>(Xb1, Wt2, deg, b2, H, Xb2, psum + NH, NH);
    fixup_kernel<<<1, NH, 0, stream>>>(H, deg, edges, cnt, b2, Xb2, psum, 1, nullptr);
    // layer 3: A = Xb2 -> Xb1  (fixup also finalizes the output)
    gemm_fused_kernel<<<ggrid, 256, 0, stream>>>(Xb2, Wt3, deg, b3, H, Xb1, psum + 2 * NH, NH);
    fixup_kernel<<<1, NH, 0, stream>>>(H, deg, edges, cnt, b3, Xb1, psum, 2, out);
}

// Round 16
// 119.731 us; speedup vs baseline: 1.2878x; 1.0689x over previous
//
#include <hip/hip_runtime.h>

#define N 8192
#define F 500
#define K2 512                        // F padded to MFMA-friendly K
#define NH 256
#define CAP (1 << 17)
#define BT 128                        // dist tile
#define NBT (N / BT)                  // 64
#define TRI2 (NBT * (NBT + 1) / 2)    // 2080 (%8==0)
#define MARGIN 16.0f                  // |d_fp8 - d_exact| safety bound for pass-2 filter

using bf16x8 = __attribute__((ext_vector_type(8))) short;
using f32x4  = __attribute__((ext_vector_type(4))) float;

__device__ __forceinline__ unsigned short f32_to_bf16(float x) {
    unsigned u = __float_as_uint(x);
    u += 0x7fffu + ((u >> 16) & 1u);   // RTNE
    return (unsigned short)(u >> 16);
}
__device__ __forceinline__ float bf16_to_f32(unsigned short h) {
    return __uint_as_float(((unsigned)h) << 16);
}

// 32-k bf16 plane: [rows][32 bf16] (64 B rows), 2-bit XOR swizzle
__device__ __forceinline__ bf16x8 frag_ld32(const unsigned short* plane, int r, int k2b) {
    int k2 = k2b ^ (((r >> 1) & 3) << 4);
    return *(const bf16x8*)((const char*)plane + r * 64 + k2);
}
// 64-k bf16 plane: [rows][64 bf16] (128 B rows), 3-bit XOR swizzle (16B slot ^= r&7)
__device__ __forceinline__ bf16x8 frag_ld64(const unsigned short* plane, int r, int k2b) {
    int k2 = k2b ^ ((r & 7) << 4);
    return *(const bf16x8*)((const char*)plane + r * 128 + k2);
}
// fp8 plane: [rows][64 fp8] (64 B rows), XOR 16-B slot with (r>>1)&3 -> 2-way (free)
__device__ __forceinline__ long frag_f8(const unsigned char* plane, int r, int b) {
    int sw = ((((b >> 4) ^ ((r >> 1) & 3)) << 4) | (b & 15));
    return *(const long*)(plane + r * 64 + sw);
}

// ---------------- prep (blocks < N) + wconv (blocks >= N) ----------------
__global__ void prep_kernel(const float* __restrict__ X,
                            const float* __restrict__ W1, const float* __restrict__ W2,
                            const float* __restrict__ W3,
                            unsigned short* __restrict__ Xh, unsigned short* __restrict__ Xl,
                            unsigned char* __restrict__ Xf8,
                            float* __restrict__ sq, float* __restrict__ deg,
                            float* __restrict__ psum, unsigned* __restrict__ tmax,
                            unsigned* __restrict__ cnt,
                            unsigned short* __restrict__ Wt1, unsigned short* __restrict__ Wt2,
                            unsigned short* __restrict__ Wt3) {
    int bid = blockIdx.x;
    if (bid >= N) {   // weight transpose+convert
        int q = bid - N;
        int n = q & (NH - 1), which = q >> 8;
        const float* W = which == 0 ? W1 : (which == 1 ? W2 : W3);
        unsigned short* Wt = which == 0 ? Wt1 : (which == 1 ? Wt2 : Wt3);
        int K = which == 0 ? F : NH;
        int Kp = which == 0 ? K2 : NH;
        for (int k = threadIdx.x; k < Kp; k += 256) {
            float v = (k < K) ? W[(size_t)k * NH + n] : 0.f;
            Wt[(size_t)n * Kp + k] = f32_to_bf16(v);
        }
        return;
    }
    __shared__ float red[256];
    int i = bid;
    int t = threadIdx.x;
    if (t == 0) deg[i] = 1.0f;     // self-loop
    if (i == 0) {
        for (int k = t; k < 3 * NH; k += 256) psum[k] = 0.f;
        if (t == 0) { *tmax = 0u; *cnt = 0u; }
    }
    int k0 = 2 * t;
    float x0 = 0.f, x1 = 0.f;
    if (k0 + 1 < F) {   // F=500 even: t<250 loads a full float2
        float2 v = *(const float2*)(X + (size_t)i * F + k0);
        x0 = v.x; x1 = v.y;
    }
    unsigned short h0 = f32_to_bf16(x0), h1 = f32_to_bf16(x1);
    float r0 = x0 - bf16_to_f32(h0), r1 = x1 - bf16_to_f32(h1);
    *(unsigned*)(Xh + (size_t)i * K2 + k0) = (unsigned)h0 | ((unsigned)h1 << 16);
    *(unsigned*)(Xl + (size_t)i * K2 + k0) =
        (unsigned)f32_to_bf16(r0) | ((unsigned)f32_to_bf16(r1) << 16);
    int pk = __builtin_amdgcn_cvt_pk_fp8_f32(x0, x1, 0, false);
    *(unsigned short*)(Xf8 + (size_t)i * K2 + k0) = (unsigned short)(pk & 0xffff);

    red[t] = x0 * x0 + x1 * x1;
    __syncthreads();
    for (int off = 128; off > 0; off >>= 1) {
        if (t < off) red[t] += red[t + off];
        __syncthreads();
    }
    if (t == 0) sq[i] = red[0];
}

// ---------------- triangular block decode (nb x nb upper-tri) ----------------
__device__ __forceinline__ void tri_decode(int L, int nb, int& bi, int& bj) {
    float a = (float)(2 * nb + 1);
    bi = (int)((a - sqrtf(a * a - 8.0f * (float)L)) * 0.5f);
    if (bi < 0) bi = 0;
    if (bi > nb - 1) bi = nb - 1;
    while (bi > 0 && bi * nb - bi * (bi - 1) / 2 > L) --bi;
    while (bi < nb - 1 && (bi + 1) * nb - (bi + 1) * bi / 2 <= L) ++bi;
    bj = bi + (L - (bi * nb - bi * (bi - 1) / 2));
}

// ---------------- PASS 1: fp8 distances, 128^2 tile, 8 waves (2x4 of 64x32), dbuf ----------------
__global__ __launch_bounds__(512) void distmax_kernel(const unsigned char* __restrict__ Xf8,
                                                      const float* __restrict__ sq,
                                                      unsigned* __restrict__ tmax,
                                                      float* __restrict__ blockmin) {
    int L = (blockIdx.x % 8) * (TRI2 / 8) + blockIdx.x / 8;  // XCD swizzle (2080%8==0)
    int bi, bj;
    tri_decode(L, NBT, bi, bj);

    __shared__ __align__(16) unsigned char P[2][2][BT][64];  // [buf][A/B] fp8 = 32 KB
    __shared__ float red[16];

    int tid = threadIdx.x;
    int w = tid >> 6;                 // 8 waves: wm = w>>2 (2 in M), wn = w&3 (4 in N)
    int wm = w >> 2, wn = w & 3;
    int lane = tid & 63;
    int lr = lane & 15;

    int gi0 = bi * BT, gj0 = bj * BT;

    // staging: waves 0-3 -> A plane (32-row chunks), waves 4-7 -> B plane
    const unsigned char* srcb = Xf8 + (size_t)((w < 4) ? gi0 : gj0) * K2;
    int pidx = (w < 4) ? 0 : 1;
    int rowbase = (w & 3) * 32;
    int srw = lane >> 2;          // row-in-chunk 0..15
    int slot = lane & 3;          // 16-B slot 0..3

    auto STAGE = [&](int buf, int kc) {   // 2 global_load_lds per wave
        unsigned char* plane_w = &P[buf][pidx][0][0];
#pragma unroll
        for (int c = 0; c < 2; ++c) {
            int row = rowbase + c * 16 + srw;
            const unsigned char* g = srcb + (size_t)row * K2 + kc
                                   + ((slot ^ ((row >> 1) & 3)) << 4);
            __builtin_amdgcn_global_load_lds((const void*)g,
                (void*)(plane_w + (rowbase + c * 16) * 64), 16, 0, 0);
        }
    };

    f32x4 acc[4][2] = {};

    STAGE(0, 0);
    __syncthreads();              // buf0 staged
#pragma unroll
    for (int t = 0; t < K2 / 64; ++t) {
        const int c = t & 1;
        if (t + 1 < K2 / 64) STAGE(c ^ 1, (t + 1) * 64);  // prefetch next into free buf
#pragma unroll
        for (int ks = 0; ks < 2; ++ks) {
            int b = ks * 32 + ((lane >> 4) << 3);
            long af[4], bf[2];
#pragma unroll
            for (int mf = 0; mf < 4; ++mf) af[mf] = frag_f8(&P[c][0][0][0], wm * 64 + mf * 16 + lr, b);
#pragma unroll
            for (int nf = 0; nf < 2; ++nf) bf[nf] = frag_f8(&P[c][1][0][0], wn * 32 + nf * 16 + lr, b);
#pragma unroll
            for (int mf = 0; mf < 4; ++mf)
#pragma unroll
                for (int nf = 0; nf < 2; ++nf)
                    acc[mf][nf] = __builtin_amdgcn_mfma_f32_16x16x32_fp8_fp8(af[mf], bf[nf], acc[mf][nf], 0, 0, 0);
        }
        __syncthreads();   // all waves done reading buf c; prefetch drained -> next buf ready
    }

    // epilogue: C/D layout col = lane&15, row = (lane>>4)*4 + reg
    int gi = gi0 + wm * 64, gj = gj0 + wn * 32;
    int rbase = (lane >> 4) << 2;
    float sj[2];
#pragma unroll
    for (int nf = 0; nf < 2; ++nf) sj[nf] = sq[gj + nf * 16 + lr];

    float mmax = 0.f, mmin = 3e38f;
#pragma unroll
    for (int mf = 0; mf < 4; ++mf)
#pragma unroll
        for (int r = 0; r < 4; ++r) {
            int i = gi + mf * 16 + rbase + r;
            float si = sq[i];
#pragma unroll
            for (int nf = 0; nf < 2; ++nf) {
                int j = gj + nf * 16 + lr;
                if (j > i) {
                    float d = si + sj[nf] - 2.0f * acc[mf][nf][r];
                    mmax = fmaxf(mmax, d);
                    mmin = fminf(mmin, d);
                }
            }
        }
    for (int off = 32; off > 0; off >>= 1) {
        mmax = fmaxf(mmax, __shfl_xor(mmax, off, 64));
        mmin = fminf(mmin, __shfl_xor(mmin, off, 64));
    }
    if (lane == 0) { red[w * 2] = mmax; red[w * 2 + 1] = mmin; }
    __syncthreads();
    if (tid == 0) {
        float M = red[0], m = red[1];
#pragma unroll
        for (int q = 1; q < 8; ++q) { M = fmaxf(M, red[q * 2]); m = fminf(m, red[q * 2 + 1]); }
        atomicMax(tmax, __float_as_uint(M));   // d >= 0, bit-compare valid
        blockmin[L] = m;
    }
}

// ---------------- PASS 2: exact (3-plane bf16) edges, only on candidate blocks ----------------
__global__ __launch_bounds__(256) void edges_kernel(const unsigned short* __restrict__ Xh,
                                                    const unsigned short* __restrict__ Xl,
                                                    const float* __restrict__ sq,
                                                    const unsigned* __restrict__ tmax,
                                                    const float* __restrict__ blockmin,
                                                    unsigned* __restrict__ cnt,
                                                    int2* __restrict__ edges,
                                                    float* __restrict__ deg) {
    int L = (blockIdx.x % 8) * (TRI2 / 8) + blockIdx.x / 8;
    float t = 0.5f * __uint_as_float(*tmax);
    if (!(blockmin[L] < t + MARGIN)) return;
    int bi, bj;
    tri_decode(L, NBT, bi, bj);

    __shared__ __align__(16) unsigned short planes[4][BT][32];  // Ah, Al, Bh, Bl = 32 KB

    int tid = threadIdx.x;
    int w = tid >> 6;
    int wm = w >> 1, wn = w & 1;
    int lane = tid & 63;
    int lr = lane & 15;
    int k2b = (lane >> 4) << 4;

    int gi0 = bi * BT, gj0 = bj * BT;

    const unsigned short* srcbase = (w & 1) ? Xl : Xh;
    int grow0 = (w < 2) ? gi0 : gj0;
    unsigned short* plane_w = &planes[w][0][0];

    int srow = lane >> 2;
    int sk2 = ((lane & 3) << 4);

    f32x4 acc[4][4] = {};

    for (int kc = 0; kc < K2; kc += 32) {
        __syncthreads();
#pragma unroll
        for (int c = 0; c < 8; ++c) {
            int row = c * 16 + srow;
            int k2 = sk2 ^ (((row >> 1) & 3) << 4);
            const char* g = (const char*)(srcbase + (size_t)(grow0 + row) * K2 + kc) + k2;
            __builtin_amdgcn_global_load_lds((const void*)g, (void*)((char*)plane_w + c * 1024), 16, 0, 0);
        }
        __syncthreads();

        bf16x8 ahf[4], alf[4], bhf[4], blf[4];
#pragma unroll
        for (int mf = 0; mf < 4; ++mf) {
            int r = wm * 64 + mf * 16 + lr;
            ahf[mf] = frag_ld32(&planes[0][0][0], r, k2b);
            alf[mf] = frag_ld32(&planes[1][0][0], r, k2b);
        }
#pragma unroll
        for (int nf = 0; nf < 4; ++nf) {
            int r = wn * 64 + nf * 16 + lr;
            bhf[nf] = frag_ld32(&planes[2][0][0], r, k2b);
            blf[nf] = frag_ld32(&planes[3][0][0], r, k2b);
        }
#pragma unroll
        for (int mf = 0; mf < 4; ++mf)
#pragma unroll
            for (int nf = 0; nf < 4; ++nf) {
                acc[mf][nf] = __builtin_amdgcn_mfma_f32_16x16x32_bf16(ahf[mf], bhf[nf], acc[mf][nf], 0, 0, 0);
                acc[mf][nf] = __builtin_amdgcn_mfma_f32_16x16x32_bf16(ahf[mf], blf[nf], acc[mf][nf], 0, 0, 0);
                acc[mf][nf] = __builtin_amdgcn_mfma_f32_16x16x32_bf16(alf[mf], bhf[nf], acc[mf][nf], 0, 0, 0);
            }
    }

    int gi = gi0 + wm * 64, gj = gj0 + wn * 64;
    int rbase = (lane >> 4) << 2;
    float sj[4];
#pragma unroll
    for (int nf = 0; nf < 4; ++nf) sj[nf] = sq[gj + nf * 16 + lr];

#pragma unroll
    for (int mf = 0; mf < 4; ++mf)
#pragma unroll
        for (int r = 0; r < 4; ++r) {
            int i = gi + mf * 16 + rbase + r;
            float si = sq[i];
#pragma unroll
            for (int nf = 0; nf < 4; ++nf) {
                int j = gj + nf * 16 + lr;
                if (j > i) {
                    float d = si + sj[nf] - 2.0f * acc[mf][nf][r];
                    if (d < t) {
                        unsigned p = atomicAdd(cnt, 1u);
                        if (p < (unsigned)CAP) edges[p] = make_int2(i, j);
                        atomicAdd(&deg[j], 1.0f);
                    }
                }
            }
        }
}

// ---------------- MFMA GEMM 64x64, KS=64, counted-vmcnt + fused epilogue ----------------
__global__ __launch_bounds__(256) void gemm_fused_kernel(const unsigned short* __restrict__ A,
                                                         const unsigned short* __restrict__ Wt,
                                                         const float* __restrict__ deg,
                                                         const float* __restrict__ b,
                                                         float* __restrict__ H,
                                                         unsigned short* __restrict__ Xbo,
                                                         float* __restrict__ psum, int Kp) {
    __shared__ __align__(16) unsigned short P[2][2][64][64];  // [buf][A/B] = 32 KB
    int bm = blockIdx.x, bn = blockIdx.y;
    int tid = threadIdx.x;
    int w = tid >> 6;
    int wm = w >> 1, wn = w & 1;      // 2x2 waves, 32x32 each
    int lane = tid & 63;
    int lr = lane & 15;

    int gm0 = bm * 64, gn0 = bn * 64;

    const unsigned short* srcbase = (w < 2) ? A + (size_t)gm0 * Kp : Wt + (size_t)gn0 * Kp;
    int pidx = (w < 2) ? 0 : 1;
    int rowbase = (w & 1) * 32;
    int sr8 = lane >> 3;              // row-in-chunk 0..7
    int sl8 = lane & 7;               // 16-B slot 0..7 within 128-B row

    auto STAGE = [&](int buf, int kc) {   // 4 global_load_lds per wave
        char* dst = (char*)&P[buf][pidx][0][0];
#pragma unroll
        for (int c = 0; c < 4; ++c) {
            int row = rowbase + c * 8 + sr8;
            const char* g = (const char*)srcbase + ((size_t)row * Kp + kc) * 2
                          + ((sl8 ^ (row & 7)) << 4);
            __builtin_amdgcn_global_load_lds((const void*)g,
                (void*)(dst + (rowbase + c * 8) * 128), 16, 0, 0);
        }
    };

    f32x4 acc[2][2] = {};

    int nt = Kp / 64;
    STAGE(0, 0);
    STAGE(1, 64);
    for (int t = 0; t < nt; ++t) {
        const int c = t & 1;
        if (t < nt - 1) { asm volatile("s_waitcnt vmcnt(4)" ::: "memory"); }
        else            { asm volatile("s_waitcnt vmcnt(0)" ::: "memory"); }
        __builtin_amdgcn_sched_barrier(0);
        __builtin_amdgcn_s_barrier();
        const unsigned short* pA = &P[c][0][0][0];
        const unsigned short* pB = &P[c][1][0][0];
#pragma unroll
        for (int ks = 0; ks < 2; ++ks) {
            int k2b = ks * 64 + ((lane >> 4) << 4);
            bf16x8 af[2], bfr[2];
#pragma unroll
            for (int mf = 0; mf < 2; ++mf) af[mf] = frag_ld64(pA, wm * 32 + mf * 16 + lr, k2b);
#pragma unroll
            for (int nf = 0; nf < 2; ++nf) bfr[nf] = frag_ld64(pB, wn * 32 + nf * 16 + lr, k2b);
            __builtin_amdgcn_s_setprio(1);
#pragma unroll
            for (int mf = 0; mf < 2; ++mf)
#pragma unroll
                for (int nf = 0; nf < 2; ++nf)
                    acc[mf][nf] = __builtin_amdgcn_mfma_f32_16x16x32_bf16(af[mf], bfr[nf], acc[mf][nf], 0, 0, 0);
            __builtin_amdgcn_s_setprio(0);
        }
        asm volatile("s_waitcnt lgkmcnt(0)" ::: "memory");
        __builtin_amdgcn_sched_barrier(0);
        __builtin_amdgcn_s_barrier();
        if (t + 2 < nt) STAGE(c, (t + 2) * 64);
    }

    // fused epilogue: H raw, Xb = bf16(relu(H/deg + b)), psum += column sums
    int rbase = (lane >> 4) << 2;
    float bias[2], ps[2] = {0.f, 0.f};
    int col[2];
#pragma unroll
    for (int nf = 0; nf < 2; ++nf) { col[nf] = gn0 + wn * 32 + nf * 16 + lr; bias[nf] = b[col[nf]]; }
#pragma unroll
    for (int mf = 0; mf < 2; ++mf)
#pragma unroll
        for (int r = 0; r < 4; ++r) {
            int row = gm0 + wm * 32 + mf * 16 + rbase + r;
            float dv = deg[row];
#pragma unroll
            for (int nf = 0; nf < 2; ++nf) {
                float hraw = acc[mf][nf][r];
                size_t idx = (size_t)row * NH + col[nf];
                H[idx] = hraw;
                float v = fmaxf(hraw / dv + bias[nf], 0.f);
                Xbo[idx] = f32_to_bf16(v);
                ps[nf] += v;
            }
        }
#pragma unroll
    for (int nf = 0; nf < 2; ++nf) {
        ps[nf] += __shfl_xor(ps[nf], 16, 64);
        ps[nf] += __shfl_xor(ps[nf], 32, 64);
        if (lane < 16) atomicAdd(&psum[col[nf]], ps[nf]);
    }
}

// ---------------- edge fixup (+ fused finalize on the last layer) ----------------
__global__ void fixup_kernel(const float* __restrict__ H, const float* __restrict__ deg,
                             const int2* __restrict__ edges, const unsigned* __restrict__ cnt,
                             const float* __restrict__ b, unsigned short* __restrict__ Xbo,
                             float* __restrict__ psum, int layer, float* __restrict__ out) {
    int f = threadIdx.x;
    unsigned n = *cnt;
    if (n > 4096u) n = 4096u;
    float bias = b[f];
    float dpsum = 0.f;
    for (unsigned e = 0; e < n; ++e) {
        int j = edges[e].y;
        bool dup = false;
        for (unsigned e2 = 0; e2 < e; ++e2)
            if (edges[e2].y == j) { dup = true; break; }
        if (dup) continue;
        float base = H[(size_t)j * NH + f] / deg[j] + bias;   // matches gemm epilogue math
        float accv = base;
        for (unsigned e2 = e; e2 < n; ++e2)
            if (edges[e2].y == j) {
                int i = edges[e2].x;
                accv += (1.0f / sqrtf(deg[i])) * (1.0f / sqrtf(deg[j])) * H[(size_t)i * NH + f];
            }
        float oldv = fmaxf(base, 0.f);
        float newv = fmaxf(accv, 0.f);
        dpsum += newv - oldv;
        Xbo[(size_t)j * NH + f] = f32_to_bf16(newv);
    }
    psum[layer * NH + f] += dpsum;   // single block; thread f owns psum[.][f]
    if (out) {
        float p = (psum[f] + psum[NH + f] + psum[2 * NH + f]) * (1.0f / (float)N);
        out[f] = p;
        out[NH + f] = p;
    }
}

static inline size_t align_up(size_t x, size_t a) { return (x + a - 1) & ~(a - 1); }

extern "C" void kernel_launch(void* const* d_in, const int* in_sizes, int n_in,
                              void* d_out, int out_size, void* d_ws, size_t ws_size,
                              hipStream_t stream) {
    const float* feature = (const float*)d_in[0];
    const float* W1 = (const float*)d_in[1];
    const float* b1 = (const float*)d_in[2];
    const float* W2 = (const float*)d_in[3];
    const float* b2 = (const float*)d_in[4];
    const float* W3 = (const float*)d_in[5];
    const float* b3 = (const float*)d_in[6];
    float* out = (float*)d_out;

    char* w = (char*)d_ws;
    size_t off = 0;
    float* sq = (float*)(w + off);         off += (size_t)N * 4;
    float* deg = (float*)(w + off);        off += (size_t)N * 4;
    float* psum = (float*)(w + off);       off += 3 * NH * 4;
    unsigned* tmax = (unsigned*)(w + off); off += 4;
    unsigned* cnt = (unsigned*)(w + off);  off += 4;
    off = align_up(off, 256);
    float* blockmin = (float*)(w + off);   off += (size_t)TRI2 * 4;
    off = align_up(off, 256);
    int2* edges = (int2*)(w + off);        off += (size_t)CAP * 8;
    off = align_up(off, 256);
    float* H = (float*)(w + off);          off += (size_t)N * NH * 4;
    off = align_up(off, 256);
    unsigned short* Xh = (unsigned short*)(w + off);  off += (size_t)N * K2 * 2;
    unsigned short* Xl = (unsigned short*)(w + off);  off += (size_t)N * K2 * 2;
    unsigned char* Xf8 = (unsigned char*)(w + off);   off += (size_t)N * K2;
    unsigned short* Wt1 = (unsigned short*)(w + off); off += (size_t)NH * K2 * 2;
    unsigned short* Wt2 = (unsigned short*)(w + off); off += (size_t)NH * NH * 2;
    unsigned short* Wt3 = (unsigned short*)(w + off); off += (size_t)NH * NH * 2;
    unsigned short* Xb1 = (unsigned short*)(w + off); off += (size_t)N * NH * 2;
    unsigned short* Xb2 = (unsigned short*)(w + off); off += (size_t)N * NH * 2;

    prep_kernel<<<N + 3 * NH, 256, 0, stream>>>(feature, W1, W2, W3, Xh, Xl, Xf8, sq, deg,
                                                psum, tmax, cnt, Wt1, Wt2, Wt3);
    distmax_kernel<<<TRI2, 512, 0, stream>>>(Xf8, sq, tmax, blockmin);
    edges_kernel<<<TRI2, 256, 0, stream>>>(Xh, Xl, sq, tmax, blockmin, cnt, edges, deg);

    dim3 ggrid(N / 64, NH / 64);
    // layer 1: A = Xh (bf16 hi plane, K=512) -> Xb1
    gemm_fused_kernel<<<ggrid, 256, 0, stream>>>(Xh, Wt1, deg, b1, H, Xb1, psum, K2);
    fixup_kernel<<<1, NH, 0, stream>>>(H, deg, edges, cnt, b1, Xb1, psum, 0, nullptr);
    // layer 2: A = Xb1 -> Xb2
    gemm_fused_kernel<<<ggrid, 256, 0, stream>>>(Xb1, Wt2, deg, b2, H, Xb2, psum + NH, NH);
    fixup_kernel<<<1, NH, 0, stream>>>(H, deg, edges, cnt, b2, Xb2, psum, 1, nullptr);
    // layer 3: A = Xb2 -> Xb1  (fixup also finalizes the output)
    gemm_fused_kernel<<<ggrid, 256, 0, stream>>>(Xb2, Wt3, deg, b3, H, Xb1, psum + 2 * NH, NH);
    fixup_kernel<<<1, NH, 0, stream>>>(H, deg, edges, cnt, b3, Xb1, psum, 2, out);
}